// Round 10
// baseline (55.727 us; speedup 1.0000x reference)
//
#include <hip/hip_runtime.h>
#include <hip/hip_bf16.h>

typedef __attribute__((ext_vector_type(4))) float f32x4;
typedef __attribute__((ext_vector_type(8))) short s16x8;
typedef __attribute__((ext_vector_type(4))) short s16x4;

#define M_DIM 256
#define N_DIM 16384
#define K_DIM 2048
#define BN 64
#define BK 64
#define NKT 32              // K tiles of 64
#define TEMP_INV 20.0f
#define SPECIAL 5554
#define IGNORE_IDX 1023

__device__ __forceinline__ short f2bf(float x) {
  __hip_bfloat16 h = __float2bfloat16(x);
  return __builtin_bit_cast(short, h);
}

__device__ __forceinline__ void gload_lds16(const void* g, void* l) {
  __builtin_amdgcn_global_load_lds((const __attribute__((address_space(1))) void*)g,
                                   (__attribute__((address_space(3))) void*)l, 16, 0, 0);
}

// inputs f32 [256][2048] -> bf16 image for linear global_load_lds.
// Tile kt: 2048 chunks of 16B; chunk c: row = c>>3, s' = c&7, s = s'^(row&7);
// holds A[row][kt*64 + s*8 .. +8]. GEMM reads with the matching XOR.
__global__ __launch_bounds__(256) void convA(const float* __restrict__ A,
                                             short* __restrict__ Abf) {
  int fid = blockIdx.x * 256 + threadIdx.x;   // 0..65535
  int kt = fid >> 11;
  int c = fid & 2047;
  int row = c >> 3;
  int s = (c & 7) ^ (row & 7);
  const float* src = A + (size_t)row * K_DIM + kt * BK + s * 8;
  float4 lo = *(const float4*)src;
  float4 hi = *(const float4*)(src + 4);
  s16x8 h;
  h[0] = f2bf(lo.x); h[1] = f2bf(lo.y); h[2] = f2bf(lo.z); h[3] = f2bf(lo.w);
  h[4] = f2bf(hi.x); h[5] = f2bf(hi.y); h[6] = f2bf(hi.z); h[7] = f2bf(hi.w);
  *reinterpret_cast<s16x8*>(Abf + (size_t)fid * 8) = h;
}

// Fused GEMM + exp-rowsum + target capture. BM=256: B read ONCE (256 MB total
// staged bytes). Depth-3 LDS ring, >=2-iter load slack, compiler-counted waits
// only (no manual vmcnt in the loop), raw lgkm barrier.
__global__ __launch_bounds__(512, 1) void gemm_fused(
    const short* __restrict__ Abf, const float* __restrict__ B,
    const int* __restrict__ targets,
    float* __restrict__ partial,    // [256 bn][256 rows]
    float* __restrict__ targ) {     // [256]
  __shared__ __align__(16) short Al[3][M_DIM * BK];  // 3 x 32 KB
  __shared__ __align__(16) short Bl[3][BN * BK];     // 3 x 8 KB
  __shared__ int tcs[M_DIM];
  __shared__ float rsum[M_DIM][2];

  int bn = blockIdx.x;            // 0..255, one 64-col B panel each
  int tid = threadIdx.x;
  int wave = tid >> 6;
  int lane = tid & 63;
  int rl = lane & 15;
  int kq = lane >> 4;             // 0..3
  int wm = wave >> 1;             // 0..3 -> rows wm*64..+63
  int wn = wave & 1;              // 0..1 -> cols wn*32..+31

  if (tid < M_DIM) {
    int tt = targets[tid] - 1;
    if (tt == SPECIAL) tt = IGNORE_IDX;
    tcs[tid] = tt < 0 ? 0 : (tt > N_DIM - 1 ? N_DIM - 1 : tt);
  }

  // B staging map: row = tid>>3 (0..63), quad = tid&7; two float4 at
  // k = quad*4 and quad*4+32. 8 lanes x 16B = 128B contiguous per row.
  const float* bbase = B + ((size_t)bn * BN + (tid >> 3)) * K_DIM + (tid & 7) * 4;

  f32x4 acc[4][2];
#pragma unroll
  for (int m = 0; m < 4; ++m)
#pragma unroll
    for (int n = 0; n < 2; ++n) acc[m][n] = f32x4{0.f, 0.f, 0.f, 0.f};

  float4 S0[2], S1[2];   // B reg sets, static indices only

#define ADMA(t, buf)                                                          \
  { _Pragma("unroll") for (int _j = 0; _j < 4; ++_j) {                        \
      int _c = _j * 512 + tid;                                                \
      gload_lds16(Abf + (((size_t)(t) * 2048 + _c) << 3),                     \
                  (char*)&Al[buf][0] + (size_t)_c * 16);                      \
  } }

#define BGLB(t, R)                                                            \
  { const float* _p = bbase + (size_t)(t) * BK;                               \
    R[0] = *(const float4*)_p;                                                \
    R[1] = *(const float4*)(_p + 32); }

// write B tile into slot buf: slot index s (0..7) with XOR(row&7); thread's
// two float4 cover slots quad>>1 and 4+(quad>>1), half = quad&1.
#define CVTW(R, buf)                                                          \
  { int _row = tid >> 3, _q = tid & 7;                                        \
    int _s0 = (_q >> 1), _h = (_q & 1);                                       \
    int _o0 = _row * 64 + (((_s0) ^ (_row & 7)) << 3) + _h * 4;               \
    int _o1 = _row * 64 + (((_s0 + 4) ^ (_row & 7)) << 3) + _h * 4;           \
    s16x4 _a, _b;                                                             \
    _a[0] = f2bf(R[0].x); _a[1] = f2bf(R[0].y);                               \
    _a[2] = f2bf(R[0].z); _a[3] = f2bf(R[0].w);                               \
    _b[0] = f2bf(R[1].x); _b[1] = f2bf(R[1].y);                               \
    _b[2] = f2bf(R[1].z); _b[3] = f2bf(R[1].w);                               \
    *reinterpret_cast<s16x4*>(&Bl[buf][0] + _o0) = _a;                        \
    *reinterpret_cast<s16x4*>(&Bl[buf][0] + _o1) = _b; }

#define COMPUTE(par)                                                          \
  { const short* _al = &Al[par][0]; const short* _bl = &Bl[par][0];           \
    _Pragma("unroll") for (int _kk = 0; _kk < 2; ++_kk) {                     \
      s16x8 _af[4], _bf[2];                                                   \
      int _s = _kk * 4 + kq;                                                  \
      _Pragma("unroll") for (int _m = 0; _m < 4; ++_m) {                      \
        int _row = wm * 64 + _m * 16 + rl;                                    \
        _af[_m] = *reinterpret_cast<const s16x8*>(                            \
            _al + (((_row << 3) + (_s ^ (_row & 7))) << 3));                  \
      }                                                                       \
      _Pragma("unroll") for (int _n = 0; _n < 2; ++_n) {                      \
        int _row = wn * 32 + _n * 16 + rl;                                    \
        _bf[_n] = *reinterpret_cast<const s16x8*>(                            \
            _bl + (((_row << 3) + (_s ^ (_row & 7))) << 3));                  \
      }                                                                       \
      _Pragma("unroll") for (int _m = 0; _m < 4; ++_m)                        \
          _Pragma("unroll") for (int _n = 0; _n < 2; ++_n)                    \
              acc[_m][_n] = __builtin_amdgcn_mfma_f32_16x16x32_bf16(          \
                  _af[_m], _bf[_n], acc[_m][_n], 0, 0, 0);                    \
    } }

#define VMCNT0() asm volatile("s_waitcnt vmcnt(0)" ::: "memory")
#define BARRIER() asm volatile("s_waitcnt lgkmcnt(0)\n\ts_barrier" ::: "memory")

  // Iter t (between B_t and B_{t+1}): slot (t+2)%3 became writable at B_t.
  // Issue ADMA(t+2)+BGLB(t+3) first; COMPUTE(t); CVTW publishes B(t+2) with a
  // compiler-counted vmcnt (6 younger ops stay in flight). Transitive DMA
  // guarantee: CVTW waits BGLB(t+2) [issued iter t-1 AFTER ADMA(t+1)], so each
  // wave's ADMA(t+1) is complete before it reaches B_{t+1}.
#define ITER(T, CUR, WR, PS)                                                  \
  {                                                                           \
    ADMA((T) + 2, WR);                                                        \
    if ((T) + 3 < NKT) { BGLB((T) + 3, S##PS##_N); }                          \
    COMPUTE(CUR);                                                             \
    CVTW(S##PS, WR);                                                          \
    if ((T) + 3 >= NKT) VMCNT0();                                             \
    BARRIER();                                                                \
  }
#define S0_N S1
#define S1_N S0

  // Prologue: stage tiles 0,1 fully; pre-issue BGLB(2). One-time drain only.
  ADMA(0, 0);
  ADMA(1, 1);
  BGLB(0, S0);
  BGLB(1, S1);
  CVTW(S0, 0);     // auto vmcnt(2): B(1) stays in flight
  CVTW(S1, 1);     // auto vmcnt(0): one-time (also covers ADMA 0/1)
  BGLB(2, S0);
  BARRIER();

  for (int tb = 0; tb < 30; tb += 6) {
    ITER(tb + 0, 0, 2, 0);
    ITER(tb + 1, 1, 0, 1);
    ITER(tb + 2, 2, 1, 0);
    ITER(tb + 3, 0, 2, 1);
    ITER(tb + 4, 1, 0, 0);
    ITER(tb + 5, 2, 1, 1);
  }
  // tiles 30, 31 fully staged & published; no further writes -> no barriers.
  COMPUTE(0);   // t=30, slot 0
  COMPUTE(1);   // t=31, slot 1

  // ---- fused epilogue: exp + per-row reduce + target capture ----
  int colbase = bn * BN + wn * 32 + rl;
#pragma unroll
  for (int m = 0; m < 4; ++m) {
#pragma unroll
    for (int r = 0; r < 4; ++r) {
      int row = wm * 64 + m * 16 + kq * 4 + r;   // 0..255
      int tc = tcs[row];
      float s = 0.f;
#pragma unroll
      for (int n = 0; n < 2; ++n) {
        float logit = acc[m][n][r] * TEMP_INV;
        if (colbase + n * 16 == tc) targ[row] = logit;
        s += __expf(logit);
      }
#pragma unroll
      for (int msk = 1; msk < 16; msk <<= 1) s += __shfl_xor(s, msk, 64);
      if (rl == 0) rsum[row][wn] = s;
    }
  }
  __syncthreads();
  if (tid < M_DIM) {
    partial[(size_t)bn * M_DIM + tid] = rsum[tid][0] + rsum[tid][1];
  }
#undef ADMA
#undef BGLB
#undef CVTW
#undef COMPUTE
#undef VMCNT0
#undef BARRIER
#undef ITER
#undef S0_N
#undef S1_N
}

__global__ __launch_bounds__(256) void finalize(
    const float* __restrict__ partial, const float* __restrict__ targ,
    const int* __restrict__ targets, float* __restrict__ out) {
  int r = threadIdx.x;  // 256 rows
  float s = 0.f;
  for (int j = 0; j < 256; ++j) s += partial[(size_t)j * M_DIM + r];
  int t = targets[r] - 1;
  if (t == SPECIAL) t = IGNORE_IDX;
  bool valid = (t >= 0) && (t != IGNORE_IDX);
  float nl = logf(s) - targ[r];
  float sv = valid ? nl : 0.0f;
  float cv = valid ? 1.0f : 0.0f;
#pragma unroll
  for (int m = 1; m < 64; m <<= 1) {
    sv += __shfl_xor(sv, m, 64);
    cv += __shfl_xor(cv, m, 64);
  }
  __shared__ float ss[4], cc[4];
  int wid = r >> 6, lane = r & 63;
  if (lane == 0) { ss[wid] = sv; cc[wid] = cv; }
  __syncthreads();
  if (r == 0) {
    float S = ss[0] + ss[1] + ss[2] + ss[3];
    float C = cc[0] + cc[1] + cc[2] + cc[3];
    out[0] = S / fmaxf(C, 1.0f);
  }
}

extern "C" void kernel_launch(void* const* d_in, const int* in_sizes, int n_in,
                              void* d_out, int out_size, void* d_ws, size_t ws_size,
                              hipStream_t stream) {
  const float* inputs   = (const float*)d_in[0];  // [256, 2048]
  const int*   targets  = (const int*)d_in[1];    // [256]
  const float* features = (const float*)d_in[2];  // [16384, 2048]
  float* out = (float*)d_out;

  short* Abf     = (short*)d_ws;                        // 1 MB bf16 image
  float* partial = (float*)((char*)d_ws + (1 << 20));   // [256][256] f32 = 256 KB
  float* targ    = partial + 256 * M_DIM;               // [256] f32

  convA<<<dim3(256), dim3(256), 0, stream>>>(inputs, Abf);
  gemm_fused<<<dim3(256), dim3(512), 0, stream>>>(Abf, features, targets, partial, targ);
  finalize<<<dim3(1), dim3(256), 0, stream>>>(partial, targ, targets, out);
}